// Round 4
// baseline (333.754 us; speedup 1.0000x reference)
//
#include <hip/hip_runtime.h>
#include <hip/hip_bf16.h>

// GaussianMMD: out = mean(Kxx)+mean(Kyy)-2*mean(Kxy), K=exp(-||a-b||^2/2048)
// R4: same 256x256 8-phase pipeline as R3, MFMA shape 16x16x32 -> 32x32x16
// (2495 vs 2075 TF ceiling). Schedule/LDS/swizzle/vmcnt identical to R3.

#define N_ROWS 8192
#define DIM 1024
#define TWO_N 16384
#define BT 256
#define BK 64
#define NT2 64
#define NBLK2 (NT2 * (NT2 + 1) / 2) // 2080
#define NKT (DIM / BK)              // 16
#define INV_SIGMA (1.0f / 2048.0f)

typedef short s16x8 __attribute__((ext_vector_type(8)));
typedef float f32x4 __attribute__((ext_vector_type(4)));
typedef float f32x16 __attribute__((ext_vector_type(16)));

typedef __attribute__((address_space(3))) unsigned int lds_u32_t;
typedef const __attribute__((address_space(1))) unsigned int glb_u32_t;

__device__ __forceinline__ void gload16(const void* g, void* l) {
    __builtin_amdgcn_global_load_lds((glb_u32_t*)g, (lds_u32_t*)l, 16, 0, 0);
}

__device__ __forceinline__ unsigned short f2bf_rne(float f, float* back) {
    unsigned int u = __float_as_uint(f);
    unsigned int r = (u + 0x7fffu + ((u >> 16) & 1u)) >> 16;
    *back = __uint_as_float(r << 16);
    return (unsigned short)r;
}

#define SBAR() do { __builtin_amdgcn_sched_barrier(0); \
                    __builtin_amdgcn_s_barrier();      \
                    __builtin_amdgcn_sched_barrier(0); } while (0)

// ---- convert fp32 -> bf16, norms from bf16 ----
__global__ __launch_bounds__(256) void mmd_convert(const float* __restrict__ x,
                                                   const float* __restrict__ y,
                                                   unsigned short* __restrict__ zh,
                                                   float* __restrict__ zn) {
    int row = blockIdx.x * 4 + (threadIdx.x >> 6);
    int lane = threadIdx.x & 63;
    const float* p = (row < N_ROWS) ? (x + (size_t)row * DIM)
                                    : (y + (size_t)(row - N_ROWS) * DIM);
    unsigned short* q = zh + (size_t)row * DIM;
    float s = 0.0f;
#pragma unroll
    for (int c = 0; c < 4; ++c) {
        int idx = (lane + c * 64) * 4;
        float4 v = *(const float4*)(p + idx);
        float b0, b1, b2, b3;
        ushort4 o;
        o.x = f2bf_rne(v.x, &b0);
        o.y = f2bf_rne(v.y, &b1);
        o.z = f2bf_rne(v.z, &b2);
        o.w = f2bf_rne(v.w, &b3);
        s = fmaf(b0, b0, s);
        s = fmaf(b1, b1, s);
        s = fmaf(b2, b2, s);
        s = fmaf(b3, b3, s);
        *(ushort4*)(q + idx) = o;
    }
#pragma unroll
    for (int o = 32; o > 0; o >>= 1) s += __shfl_down(s, o);
    if (lane == 0) zn[row] = s;
}

// ---- main: 256x256 tile, 8 waves, 8-phase pipeline, 32x32x16 MFMA ----
__global__ __launch_bounds__(512, 2) void mmd_main8(const unsigned short* __restrict__ zh,
                                                    const float* __restrict__ zn,
                                                    double* __restrict__ partials) {
    __shared__ __align__(16) short lsA[2][BT * BK];  // 64 KiB
    __shared__ __align__(16) short lsB[2][BT * BK];  // 64 KiB
    __shared__ double red[8];

    const int tid = threadIdx.x;
    const int bid0 = blockIdx.x;
    const int bid = (bid0 & 7) * (NBLK2 / 8) + (bid0 >> 3);  // XCD swizzle

    int tj = (int)((sqrtf(8.0f * (float)bid + 1.0f) - 1.0f) * 0.5f);
    while ((tj + 1) * (tj + 2) / 2 <= bid) ++tj;
    while (tj * (tj + 1) / 2 > bid) --tj;
    const int ti = bid - tj * (tj + 1) / 2;

    const int rA = ti * BT, rB = tj * BT;
    const float w = ((ti < 32) == (tj < 32)) ? 1.0f : -1.0f;
    const float factor = (ti == tj) ? w : 2.0f * w;

    const int l = tid & 63;
    const int wid = tid >> 6;
    const int wr = wid >> 2;  // 0..1
    const int wc = wid & 3;   // 0..3
    const int hi = l >> 5;    // k-group half
    const int fx = l & 7;     // swizzle xor (== row&7 for frag reads)

    // staging addresses (pre-swizzled global source, linear LDS dest)
    const int rowoff = tid >> 3;
    const int kswz = ((tid & 7) ^ (rowoff & 7)) << 3;
    const unsigned short* pA = zh + (size_t)(rA + rowoff) * DIM + kswz;
    const unsigned short* pB = zh + (size_t)(rB + rowoff) * DIM + kswz;
    short* lA = &lsA[0][0];
    short* lB = &lsB[0][0];
    const int t8 = tid * 8;

#define STG_A(buf, half, kt) do {                                         \
        const unsigned short* g_ = pA + (size_t)((half) * 128) * DIM + (kt) * BK; \
        gload16(g_,            lA + (buf) * 16384 + (half) * 8192 + t8);        \
        gload16(g_ + 64 * DIM, lA + (buf) * 16384 + (half) * 8192 + 4096 + t8); \
    } while (0)
#define STG_B(buf, half, kt) do {                                         \
        const unsigned short* g_ = pB + (size_t)((half) * 128) * DIM + (kt) * BK; \
        gload16(g_,            lB + (buf) * 16384 + (half) * 8192 + t8);        \
        gload16(g_ + 64 * DIM, lB + (buf) * 16384 + (half) * 8192 + 4096 + t8); \
    } while (0)
    // 32x32 fragment reads: lane row/col = base + (l&31); k-chunk = s*2+hi
    const int aBase = (wr * 128 + (l & 31)) * 64;
    const int bBase = (wc * 64 + (l & 31)) * 64;
#define DS_A(buf, m, s) (*(const s16x8*)(lA + (buf) * 16384 + aBase + (m) * 2048 + \
        ((((s) * 2 + hi) ^ fx) << 3)))
#define DS_B(buf, n, s) (*(const s16x8*)(lB + (buf) * 16384 + bBase + (n) * 2048 + \
        ((((s) * 2 + hi) ^ fx) << 3)))

    f32x16 acc[4][2];
#pragma unroll
    for (int m = 0; m < 4; ++m)
#pragma unroll
        for (int n = 0; n < 2; ++n)
#pragma unroll
            for (int r = 0; r < 16; ++r) acc[m][n][r] = 0.0f;

    // prologue: t0.A0, t0.B0, t0.B1, t0.A1, t1.A0
    STG_A(0, 0, 0);
    STG_B(0, 0, 0);
    STG_B(0, 1, 0);
    STG_A(0, 1, 0);
    STG_A(1, 0, 1);
    asm volatile("s_waitcnt vmcnt(2)" ::: "memory");
    SBAR();

    s16x8 a[2][4], b[2][4];

    for (int C = 0; C < NKT; ++C) {
        const int cb = C & 1, nb = cb ^ 1;

        // ---- phase 0: m-half 0 x n-frag 0 ; read A(m0,m1), B(n0) ; stage (C+1).B0
#pragma unroll
        for (int i = 0; i < 2; ++i)
#pragma unroll
            for (int s = 0; s < 4; ++s) a[i][s] = DS_A(cb, i, s);
#pragma unroll
        for (int s = 0; s < 4; ++s) b[0][s] = DS_B(cb, 0, s);
        if (C < NKT - 1) STG_B(nb, 0, C + 1);
        SBAR();
        __builtin_amdgcn_s_setprio(1);
#pragma unroll
        for (int s = 0; s < 4; ++s)
#pragma unroll
            for (int i = 0; i < 2; ++i)
                acc[i][0] = __builtin_amdgcn_mfma_f32_32x32x16_bf16(a[i][s], b[0][s], acc[i][0], 0, 0, 0);
        __builtin_amdgcn_s_setprio(0);
        SBAR();

        // ---- phase 1: m-half 0 x n-frag 1 ; read B(n1) ; stage (C+1).B1 ; vmcnt
#pragma unroll
        for (int s = 0; s < 4; ++s) b[1][s] = DS_B(cb, 1, s);
        if (C < NKT - 1) {
            STG_B(nb, 1, C + 1);
            asm volatile("s_waitcnt vmcnt(6)" ::: "memory");
        } else {
            asm volatile("s_waitcnt vmcnt(0)" ::: "memory");
        }
        SBAR();
        __builtin_amdgcn_s_setprio(1);
#pragma unroll
        for (int s = 0; s < 4; ++s)
#pragma unroll
            for (int i = 0; i < 2; ++i)
                acc[i][1] = __builtin_amdgcn_mfma_f32_32x32x16_bf16(a[i][s], b[1][s], acc[i][1], 0, 0, 0);
        __builtin_amdgcn_s_setprio(0);
        SBAR();

        // ---- phase 2: m-half 1 x n-frag 0 ; read A(m2,m3) ; stage (C+1).A1
#pragma unroll
        for (int i = 0; i < 2; ++i)
#pragma unroll
            for (int s = 0; s < 4; ++s) a[i][s] = DS_A(cb, 2 + i, s);
        if (C < NKT - 1) STG_A(nb, 1, C + 1);
        SBAR();
        __builtin_amdgcn_s_setprio(1);
#pragma unroll
        for (int s = 0; s < 4; ++s)
#pragma unroll
            for (int i = 0; i < 2; ++i)
                acc[2 + i][0] = __builtin_amdgcn_mfma_f32_32x32x16_bf16(a[i][s], b[0][s], acc[2 + i][0], 0, 0, 0);
        __builtin_amdgcn_s_setprio(0);
        SBAR();

        // ---- phase 3: m-half 1 x n-frag 1 ; stage (C+2).A0 ; vmcnt
        if (C < NKT - 2) {
            STG_A(cb, 0, C + 2);
            asm volatile("s_waitcnt vmcnt(4)" ::: "memory");
        } else if (C == NKT - 2) {
            asm volatile("s_waitcnt vmcnt(2)" ::: "memory");
        }
        SBAR();
        __builtin_amdgcn_s_setprio(1);
#pragma unroll
        for (int s = 0; s < 4; ++s)
#pragma unroll
            for (int i = 0; i < 2; ++i)
                acc[2 + i][1] = __builtin_amdgcn_mfma_f32_32x32x16_bf16(a[i][s], b[1][s], acc[2 + i][1], 0, 0, 0);
        __builtin_amdgcn_s_setprio(0);
        SBAR();
    }

    // epilogue: d2 = |a|^2+|b|^2-2ab, exp-sum
    // C/D layout: col = l&31, row = (reg&3) + 8*(reg>>2) + 4*hi
    f32x4 rn4[4][4];
#pragma unroll
    for (int m = 0; m < 4; ++m)
#pragma unroll
        for (int q = 0; q < 4; ++q)
            rn4[m][q] = *(const f32x4*)&zn[rA + wr * 128 + m * 32 + q * 8 + 4 * hi];
    float cn[2];
    cn[0] = zn[rB + wc * 64 + (l & 31)];
    cn[1] = zn[rB + wc * 64 + 32 + (l & 31)];

    float ls0 = 0.0f, ls1 = 0.0f;
#pragma unroll
    for (int m = 0; m < 4; ++m)
#pragma unroll
        for (int n = 0; n < 2; ++n)
#pragma unroll
            for (int r = 0; r < 16; ++r) {
                float d2 = fmaf(-2.0f, acc[m][n][r], rn4[m][r >> 2][r & 3] + cn[n]);
                float e = __expf(-d2 * INV_SIGMA);
                if (r & 1) ls1 += e; else ls0 += e;
            }

    double d = (double)(ls0 + ls1);
#pragma unroll
    for (int o = 32; o > 0; o >>= 1) d += __shfl_down(d, o);
    if (l == 0) red[wid] = d;
    __syncthreads();
    if (tid == 0) {
        double t = 0.0;
#pragma unroll
        for (int i = 0; i < 8; ++i) t += red[i];
        partials[blockIdx.x] = t * (double)factor;
    }
#undef STG_A
#undef STG_B
#undef DS_A
#undef DS_B
}

__global__ __launch_bounds__(256) void mmd_reduce(const double* __restrict__ partials,
                                                  float* __restrict__ out, int n) {
    __shared__ double red[256];
    double s = 0.0;
    for (int i = threadIdx.x; i < n; i += 256) s += partials[i];
    red[threadIdx.x] = s;
    __syncthreads();
    for (int ofs = 128; ofs > 0; ofs >>= 1) {
        if (threadIdx.x < ofs) red[threadIdx.x] += red[threadIdx.x + ofs];
        __syncthreads();
    }
    if (threadIdx.x == 0)
        out[0] = (float)(red[0] / ((double)N_ROWS * (double)N_ROWS));
}

// ---- fallback fp32 path (R1, proven) ----
__global__ __launch_bounds__(256) void mmd_norms_f32(const float* __restrict__ x,
                                                     const float* __restrict__ y,
                                                     float* __restrict__ zn) {
    int row = blockIdx.x * 4 + (threadIdx.x >> 6);
    int lane = threadIdx.x & 63;
    const float* p = (row < N_ROWS) ? (x + (size_t)row * DIM)
                                    : (y + (size_t)(row - N_ROWS) * DIM);
    float s = 0.0f;
#pragma unroll
    for (int c = 0; c < 4; ++c) {
        float4 v = *(const float4*)(p + (size_t)(lane + c * 64) * 4);
        s = fmaf(v.x, v.x, s);
        s = fmaf(v.y, v.y, s);
        s = fmaf(v.z, v.z, s);
        s = fmaf(v.w, v.w, s);
    }
#pragma unroll
    for (int o = 32; o > 0; o >>= 1) s += __shfl_down(s, o);
    if (lane == 0) zn[row] = s;
}

__global__ __launch_bounds__(256) void mmd_main_f32(const float* __restrict__ x,
                                                    const float* __restrict__ y,
                                                    const float* __restrict__ zn,
                                                    double* __restrict__ partials) {
    int bid = blockIdx.x;
    int tj = (int)((sqrtf(8.0f * (float)bid + 1.0f) - 1.0f) * 0.5f);
    while ((tj + 1) * (tj + 2) / 2 <= bid) ++tj;
    while (tj * (tj + 1) / 2 > bid) --tj;
    int ti = bid - tj * (tj + 1) / 2;

    const float* A = (ti < 64) ? (x + (size_t)ti * 128 * DIM)
                               : (y + (size_t)(ti - 64) * 128 * DIM);
    const float* B = (tj < 64) ? (x + (size_t)tj * 128 * DIM)
                               : (y + (size_t)(tj - 64) * 128 * DIM);
    float w = ((ti < 64) == (tj < 64)) ? 1.0f : -1.0f;
    float factor = (ti == tj) ? w : 2.0f * w;

    __shared__ float fsa[32][128];
    __shared__ float fsb[32][128];
    __shared__ double red[256];

    int tid = threadIdx.x;
    int tx = tid & 15;
    int ty = tid >> 4;

    float acc[8][8];
#pragma unroll
    for (int r = 0; r < 8; ++r)
#pragma unroll
        for (int s = 0; s < 8; ++s) acc[r][s] = 0.0f;

    for (int k0 = 0; k0 < DIM; k0 += 32) {
#pragma unroll
        for (int u = 0; u < 4; ++u) {
            int f = tid + u * 256;
            int row = f >> 3;
            int kk = (f & 7) << 2;
            float4 va = *(const float4*)(A + (size_t)row * DIM + k0 + kk);
            float4 vb = *(const float4*)(B + (size_t)row * DIM + k0 + kk);
            fsa[kk + 0][row] = va.x; fsa[kk + 1][row] = va.y;
            fsa[kk + 2][row] = va.z; fsa[kk + 3][row] = va.w;
            fsb[kk + 0][row] = vb.x; fsb[kk + 1][row] = vb.y;
            fsb[kk + 2][row] = vb.z; fsb[kk + 3][row] = vb.w;
        }
        __syncthreads();
#pragma unroll 8
        for (int k = 0; k < 32; ++k) {
            float4 a0 = *(const float4*)&fsa[k][ty * 8];
            float4 a1 = *(const float4*)&fsa[k][ty * 8 + 4];
            float4 b0 = *(const float4*)&fsb[k][tx * 8];
            float4 b1 = *(const float4*)&fsb[k][tx * 8 + 4];
            float af[8] = {a0.x, a0.y, a0.z, a0.w, a1.x, a1.y, a1.z, a1.w};
            float bfv[8] = {b0.x, b0.y, b0.z, b0.w, b1.x, b1.y, b1.z, b1.w};
#pragma unroll
            for (int r = 0; r < 8; ++r)
#pragma unroll
                for (int s = 0; s < 8; ++s)
                    acc[r][s] = fmaf(af[r], bfv[s], acc[r][s]);
        }
        __syncthreads();
    }

    float xnrm[8], ynrm[8];
#pragma unroll
    for (int r = 0; r < 8; ++r) xnrm[r] = zn[ti * 128 + ty * 8 + r];
#pragma unroll
    for (int s = 0; s < 8; ++s) ynrm[s] = zn[tj * 128 + tx * 8 + s];

    float lsum = 0.0f;
#pragma unroll
    for (int r = 0; r < 8; ++r)
#pragma unroll
        for (int s = 0; s < 8; ++s) {
            float d2 = fmaf(-2.0f, acc[r][s], xnrm[r] + ynrm[s]);
            lsum += __expf(-d2 * INV_SIGMA);
        }

    red[tid] = (double)lsum;
    __syncthreads();
#pragma unroll
    for (int ofs = 128; ofs > 0; ofs >>= 1) {
        if (tid < ofs) red[tid] += red[tid + ofs];
        __syncthreads();
    }
    if (tid == 0) partials[bid] = red[0] * (double)factor;
}

extern "C" void kernel_launch(void* const* d_in, const int* in_sizes, int n_in,
                              void* d_out, int out_size, void* d_ws, size_t ws_size,
                              hipStream_t stream) {
    const float* x = (const float*)d_in[0];
    const float* y = (const float*)d_in[1];
    float* out = (float*)d_out;

    const size_t zh_bytes = (size_t)TWO_N * DIM * sizeof(unsigned short); // 32 MiB
    const size_t zn_bytes = (size_t)TWO_N * sizeof(float);
    const size_t pt_bytes = (size_t)NBLK2 * sizeof(double);
    const size_t need = zh_bytes + zn_bytes + pt_bytes;

    if (ws_size >= need) {
        unsigned short* zh = (unsigned short*)d_ws;
        float* zn = (float*)((char*)d_ws + zh_bytes);
        double* partials = (double*)((char*)d_ws + zh_bytes + zn_bytes);
        mmd_convert<<<TWO_N / 4, 256, 0, stream>>>(x, y, zh, zn);
        mmd_main8<<<NBLK2, 512, 0, stream>>>(zh, zn, partials);
        mmd_reduce<<<1, 256, 0, stream>>>(partials, out, NBLK2);
    } else {
        float* zn = (float*)d_ws;
        double* partials = (double*)((char*)d_ws + (size_t)TWO_N * sizeof(float));
        mmd_norms_f32<<<TWO_N / 4, 256, 0, stream>>>(x, y, zn);
        mmd_main_f32<<<128 * 129 / 2, 256, 0, stream>>>(x, y, zn, partials);
        mmd_reduce<<<1, 256, 0, stream>>>(partials, out, 128 * 129 / 2);
    }
}

// Round 5
// 297.122 us; speedup vs baseline: 1.1233x; 1.1233x over previous
//
#include <hip/hip_runtime.h>
#include <hip/hip_bf16.h>

// GaussianMMD: out = mean(Kxx)+mean(Kyy)-2*mean(Kxy), K=exp(-||a-b||^2/2048)
// R5: R3's 256x256 8-phase 16x16x32 kernel with (a) watertight vmcnt schedule
// (wait -> barrier -> read, never below 2 loads in flight) and (b) even ds_read
// distribution 8/4/8/4 via one-phase lookahead of B(n0,n1).

#define N_ROWS 8192
#define DIM 1024
#define TWO_N 16384
#define BT 256
#define BK 64
#define NT2 64
#define NBLK2 (NT2 * (NT2 + 1) / 2) // 2080
#define NKT (DIM / BK)              // 16
#define INV_SIGMA (1.0f / 2048.0f)

typedef short s16x8 __attribute__((ext_vector_type(8)));
typedef float f32x4 __attribute__((ext_vector_type(4)));

typedef __attribute__((address_space(3))) unsigned int lds_u32_t;
typedef const __attribute__((address_space(1))) unsigned int glb_u32_t;

__device__ __forceinline__ void gload16(const void* g, void* l) {
    __builtin_amdgcn_global_load_lds((glb_u32_t*)g, (lds_u32_t*)l, 16, 0, 0);
}

__device__ __forceinline__ unsigned short f2bf_rne(float f, float* back) {
    unsigned int u = __float_as_uint(f);
    unsigned int r = (u + 0x7fffu + ((u >> 16) & 1u)) >> 16;
    *back = __uint_as_float(r << 16);
    return (unsigned short)r;
}

#define SBAR() do { __builtin_amdgcn_sched_barrier(0); \
                    __builtin_amdgcn_s_barrier();      \
                    __builtin_amdgcn_sched_barrier(0); } while (0)

// ---- convert fp32 -> bf16, norms from bf16 ----
__global__ __launch_bounds__(256) void mmd_convert(const float* __restrict__ x,
                                                   const float* __restrict__ y,
                                                   unsigned short* __restrict__ zh,
                                                   float* __restrict__ zn) {
    int row = blockIdx.x * 4 + (threadIdx.x >> 6);
    int lane = threadIdx.x & 63;
    const float* p = (row < N_ROWS) ? (x + (size_t)row * DIM)
                                    : (y + (size_t)(row - N_ROWS) * DIM);
    unsigned short* q = zh + (size_t)row * DIM;
    float s = 0.0f;
#pragma unroll
    for (int c = 0; c < 4; ++c) {
        int idx = (lane + c * 64) * 4;
        float4 v = *(const float4*)(p + idx);
        float b0, b1, b2, b3;
        ushort4 o;
        o.x = f2bf_rne(v.x, &b0);
        o.y = f2bf_rne(v.y, &b1);
        o.z = f2bf_rne(v.z, &b2);
        o.w = f2bf_rne(v.w, &b3);
        s = fmaf(b0, b0, s);
        s = fmaf(b1, b1, s);
        s = fmaf(b2, b2, s);
        s = fmaf(b3, b3, s);
        *(ushort4*)(q + idx) = o;
    }
#pragma unroll
    for (int o = 32; o > 0; o >>= 1) s += __shfl_down(s, o);
    if (lane == 0) zn[row] = s;
}

// ---- main: 256x256 tile, 8 waves, 4-phase/K-tile, 16x16x32 MFMA ----
__global__ __launch_bounds__(512, 2) void mmd_main8(const unsigned short* __restrict__ zh,
                                                    const float* __restrict__ zn,
                                                    double* __restrict__ partials) {
    __shared__ __align__(16) short lsA[2][BT * BK];  // 64 KiB
    __shared__ __align__(16) short lsB[2][BT * BK];  // 64 KiB
    __shared__ double red[8];

    const int tid = threadIdx.x;
    const int bid0 = blockIdx.x;
    const int bid = (bid0 & 7) * (NBLK2 / 8) + (bid0 >> 3);  // XCD swizzle

    int tj = (int)((sqrtf(8.0f * (float)bid + 1.0f) - 1.0f) * 0.5f);
    while ((tj + 1) * (tj + 2) / 2 <= bid) ++tj;
    while (tj * (tj + 1) / 2 > bid) --tj;
    const int ti = bid - tj * (tj + 1) / 2;

    const int rA = ti * BT, rB = tj * BT;
    const float w = ((ti < 32) == (tj < 32)) ? 1.0f : -1.0f;
    const float factor = (ti == tj) ? w : 2.0f * w;

    const int l = tid & 63;
    const int wid = tid >> 6;
    const int wr = wid >> 2;  // 0..1
    const int wc = wid & 3;   // 0..3
    const int fr = l & 15;
    const int fg = l >> 4;

    // staging addresses (pre-swizzled global source, linear LDS dest)
    const int rowoff = tid >> 3;
    const int kswz = ((tid & 7) ^ (rowoff & 7)) << 3;
    const unsigned short* pA = zh + (size_t)(rA + rowoff) * DIM + kswz;
    const unsigned short* pB = zh + (size_t)(rB + rowoff) * DIM + kswz;
    short* lA = &lsA[0][0];
    short* lB = &lsB[0][0];
    const int t8 = tid * 8;

#define STG_A(buf, half, kt) do {                                         \
        const unsigned short* g_ = pA + (size_t)((half) * 128) * DIM + (kt) * BK; \
        gload16(g_,            lA + (buf) * 16384 + (half) * 8192 + t8);        \
        gload16(g_ + 64 * DIM, lA + (buf) * 16384 + (half) * 8192 + 4096 + t8); \
    } while (0)
#define STG_B(buf, half, kt) do {                                         \
        const unsigned short* g_ = pB + (size_t)((half) * 128) * DIM + (kt) * BK; \
        gload16(g_,            lB + (buf) * 16384 + (half) * 8192 + t8);        \
        gload16(g_ + 64 * DIM, lB + (buf) * 16384 + (half) * 8192 + 4096 + t8); \
    } while (0)
// swizzled reads: phys slot = logical slot XOR (row&7); row&7 == fr&7 here
#define DS_A(buf, m, s) (*(const s16x8*)(lA + (buf) * 16384 + \
        (wr * 128 + (m) * 16 + fr) * BK + ((((s) * 4 + fg) ^ (fr & 7)) << 3)))
#define DS_B(buf, n, s) (*(const s16x8*)(lB + (buf) * 16384 + \
        (wc * 64 + (n) * 16 + fr) * BK + ((((s) * 4 + fg) ^ (fr & 7)) << 3)))

    f32x4 acc[8][4];
#pragma unroll
    for (int m = 0; m < 8; ++m)
#pragma unroll
        for (int n = 0; n < 4; ++n) acc[m][n] = (f32x4){0.f, 0.f, 0.f, 0.f};

    // prologue: full tile 0 + A0 of tile 1 (10 loads); retire tile 0, keep A0(1)
    STG_A(0, 0, 0);
    STG_B(0, 0, 0);
    STG_B(0, 1, 0);
    STG_A(0, 1, 0);
    STG_A(1, 0, 1);
    asm volatile("s_waitcnt vmcnt(2)" ::: "memory");
    SBAR();

    s16x8 a[4][2], b_cur[2][2], b_hi[2][2];
    // lookahead: B(n0,n1) of tile 0
#pragma unroll
    for (int j = 0; j < 2; ++j)
#pragma unroll
        for (int s = 0; s < 2; ++s) b_cur[j][s] = DS_B(0, j, s);

    for (int C = 0; C < NKT; ++C) {
        const int cb = C & 1, nb = cb ^ 1;

        // ---- p0: read A(m0-3) x8 ; stage B0(C+1) ; MFMA Q0 = acc[0..3][0..1]
#pragma unroll
        for (int i = 0; i < 4; ++i)
#pragma unroll
            for (int s = 0; s < 2; ++s) a[i][s] = DS_A(cb, i, s);
        if (C < NKT - 1) STG_B(nb, 0, C + 1);
        SBAR();
        __builtin_amdgcn_s_setprio(1);
#pragma unroll
        for (int s = 0; s < 2; ++s)
#pragma unroll
            for (int i = 0; i < 4; ++i)
#pragma unroll
                for (int j = 0; j < 2; ++j)
                    acc[i][j] = __builtin_amdgcn_mfma_f32_16x16x32_bf16(a[i][s], b_cur[j][s], acc[i][j], 0, 0, 0);
        __builtin_amdgcn_s_setprio(0);
        SBAR();

        // ---- p1: read B(n2,n3) x4 ; stage B1(C+1) ; MFMA Q1 = acc[0..3][2..3]
#pragma unroll
        for (int j = 0; j < 2; ++j)
#pragma unroll
            for (int s = 0; s < 2; ++s) b_hi[j][s] = DS_B(cb, 2 + j, s);
        if (C < NKT - 1) STG_B(nb, 1, C + 1);
        SBAR();
        __builtin_amdgcn_s_setprio(1);
#pragma unroll
        for (int s = 0; s < 2; ++s)
#pragma unroll
            for (int i = 0; i < 4; ++i)
#pragma unroll
                for (int j = 0; j < 2; ++j)
                    acc[i][2 + j] = __builtin_amdgcn_mfma_f32_16x16x32_bf16(a[i][s], b_hi[j][s], acc[i][2 + j], 0, 0, 0);
        __builtin_amdgcn_s_setprio(0);
        SBAR();

        // ---- p2: read A(m4-7) x8 ; stage A1(C+1) ; vmcnt(2) -> retires B0/B1(C+1)
        //      (protects p3's lookahead reads; barrier-separated)
#pragma unroll
        for (int i = 0; i < 4; ++i)
#pragma unroll
            for (int s = 0; s < 2; ++s) a[i][s] = DS_A(cb, 4 + i, s);
        if (C < NKT - 1) {
            STG_A(nb, 1, C + 1);
            asm volatile("s_waitcnt vmcnt(2)" ::: "memory");
        }
        SBAR();
        __builtin_amdgcn_s_setprio(1);
#pragma unroll
        for (int s = 0; s < 2; ++s)
#pragma unroll
            for (int i = 0; i < 4; ++i)
#pragma unroll
                for (int j = 0; j < 2; ++j)
                    acc[4 + i][j] = __builtin_amdgcn_mfma_f32_16x16x32_bf16(a[i][s], b_cur[j][s], acc[4 + i][j], 0, 0, 0);
        __builtin_amdgcn_s_setprio(0);
        SBAR();

        // ---- p3: lookahead read B(n0,n1) of C+1 from nb ; stage A0(C+2) ;
        //      vmcnt retires A1(C+1) (protects next p0's A-reads)
        if (C < NKT - 1) {
#pragma unroll
            for (int j = 0; j < 2; ++j)
#pragma unroll
                for (int s = 0; s < 2; ++s) b_cur[j][s] = DS_B(nb, j, s);
            if (C < NKT - 2) {
                STG_A(cb, 0, C + 2);
                asm volatile("s_waitcnt vmcnt(2)" ::: "memory");
            } else {
                asm volatile("s_waitcnt vmcnt(0)" ::: "memory");
            }
        }
        SBAR();
        __builtin_amdgcn_s_setprio(1);
#pragma unroll
        for (int s = 0; s < 2; ++s)
#pragma unroll
            for (int i = 0; i < 4; ++i)
#pragma unroll
                for (int j = 0; j < 2; ++j)
                    acc[4 + i][2 + j] = __builtin_amdgcn_mfma_f32_16x16x32_bf16(a[i][s], b_hi[j][s], acc[4 + i][2 + j], 0, 0, 0);
        __builtin_amdgcn_s_setprio(0);
        SBAR();
    }

    // epilogue: d2 = |a|^2+|b|^2-2ab, exp-sum
    float rn[8][4];
#pragma unroll
    for (int m = 0; m < 8; ++m)
#pragma unroll
        for (int v = 0; v < 4; ++v)
            rn[m][v] = zn[rA + wr * 128 + m * 16 + fg * 4 + v];
    float cn[4];
#pragma unroll
    for (int n = 0; n < 4; ++n) cn[n] = zn[rB + wc * 64 + n * 16 + fr];

    float ls0 = 0.0f, ls1 = 0.0f;
#pragma unroll
    for (int m = 0; m < 8; ++m)
#pragma unroll
        for (int n = 0; n < 4; ++n)
#pragma unroll
            for (int v = 0; v < 4; ++v) {
                float d2 = fmaf(-2.0f, acc[m][n][v], rn[m][v] + cn[n]);
                float e = __expf(-d2 * INV_SIGMA);
                if (v & 1) ls1 += e; else ls0 += e;
            }

    double d = (double)(ls0 + ls1);
#pragma unroll
    for (int o = 32; o > 0; o >>= 1) d += __shfl_down(d, o);
    if (l == 0) red[wid] = d;
    __syncthreads();
    if (tid == 0) {
        double t = 0.0;
#pragma unroll
        for (int i = 0; i < 8; ++i) t += red[i];
        partials[blockIdx.x] = t * (double)factor;
    }
#undef STG_A
#undef STG_B
#undef DS_A
#undef DS_B
}

__global__ __launch_bounds__(256) void mmd_reduce(const double* __restrict__ partials,
                                                  float* __restrict__ out, int n) {
    __shared__ double red[256];
    double s = 0.0;
    for (int i = threadIdx.x; i < n; i += 256) s += partials[i];
    red[threadIdx.x] = s;
    __syncthreads();
    for (int ofs = 128; ofs > 0; ofs >>= 1) {
        if (threadIdx.x < ofs) red[threadIdx.x] += red[threadIdx.x + ofs];
        __syncthreads();
    }
    if (threadIdx.x == 0)
        out[0] = (float)(red[0] / ((double)N_ROWS * (double)N_ROWS));
}

// ---- fallback fp32 path (R1, proven) ----
__global__ __launch_bounds__(256) void mmd_norms_f32(const float* __restrict__ x,
                                                     const float* __restrict__ y,
                                                     float* __restrict__ zn) {
    int row = blockIdx.x * 4 + (threadIdx.x >> 6);
    int lane = threadIdx.x & 63;
    const float* p = (row < N_ROWS) ? (x + (size_t)row * DIM)
                                    : (y + (size_t)(row - N_ROWS) * DIM);
    float s = 0.0f;
#pragma unroll
    for (int c = 0; c < 4; ++c) {
        float4 v = *(const float4*)(p + (size_t)(lane + c * 64) * 4);
        s = fmaf(v.x, v.x, s);
        s = fmaf(v.y, v.y, s);
        s = fmaf(v.z, v.z, s);
        s = fmaf(v.w, v.w, s);
    }
#pragma unroll
    for (int o = 32; o > 0; o >>= 1) s += __shfl_down(s, o);
    if (lane == 0) zn[row] = s;
}

__global__ __launch_bounds__(256) void mmd_main_f32(const float* __restrict__ x,
                                                    const float* __restrict__ y,
                                                    const float* __restrict__ zn,
                                                    double* __restrict__ partials) {
    int bid = blockIdx.x;
    int tj = (int)((sqrtf(8.0f * (float)bid + 1.0f) - 1.0f) * 0.5f);
    while ((tj + 1) * (tj + 2) / 2 <= bid) ++tj;
    while (tj * (tj + 1) / 2 > bid) --tj;
    int ti = bid - tj * (tj + 1) / 2;

    const float* A = (ti < 64) ? (x + (size_t)ti * 128 * DIM)
                               : (y + (size_t)(ti - 64) * 128 * DIM);
    const float* B = (tj < 64) ? (x + (size_t)tj * 128 * DIM)
                               : (y + (size_t)(tj - 64) * 128 * DIM);
    float w = ((ti < 64) == (tj < 64)) ? 1.0f : -1.0f;
    float factor = (ti == tj) ? w : 2.0f * w;

    __shared__ float fsa[32][128];
    __shared__ float fsb[32][128];
    __shared__ double red[256];

    int tid = threadIdx.x;
    int tx = tid & 15;
    int ty = tid >> 4;

    float acc[8][8];
#pragma unroll
    for (int r = 0; r < 8; ++r)
#pragma unroll
        for (int s = 0; s < 8; ++s) acc[r][s] = 0.0f;

    for (int k0 = 0; k0 < DIM; k0 += 32) {
#pragma unroll
        for (int u = 0; u < 4; ++u) {
            int f = tid + u * 256;
            int row = f >> 3;
            int kk = (f & 7) << 2;
            float4 va = *(const float4*)(A + (size_t)row * DIM + k0 + kk);
            float4 vb = *(const float4*)(B + (size_t)row * DIM + k0 + kk);
            fsa[kk + 0][row] = va.x; fsa[kk + 1][row] = va.y;
            fsa[kk + 2][row] = va.z; fsa[kk + 3][row] = va.w;
            fsb[kk + 0][row] = vb.x; fsb[kk + 1][row] = vb.y;
            fsb[kk + 2][row] = vb.z; fsb[kk + 3][row] = vb.w;
        }
        __syncthreads();
#pragma unroll 8
        for (int k = 0; k < 32; ++k) {
            float4 a0 = *(const float4*)&fsa[k][ty * 8];
            float4 a1 = *(const float4*)&fsa[k][ty * 8 + 4];
            float4 b0 = *(const float4*)&fsb[k][tx * 8];
            float4 b1 = *(const float4*)&fsb[k][tx * 8 + 4];
            float af[8] = {a0.x, a0.y, a0.z, a0.w, a1.x, a1.y, a1.z, a1.w};
            float bfv[8] = {b0.x, b0.y, b0.z, b0.w, b1.x, b1.y, b1.z, b1.w};
#pragma unroll
            for (int r = 0; r < 8; ++r)
#pragma unroll
                for (int s = 0; s < 8; ++s)
                    acc[r][s] = fmaf(af[r], bfv[s], acc[r][s]);
        }
        __syncthreads();
    }

    float xnrm[8], ynrm[8];
#pragma unroll
    for (int r = 0; r < 8; ++r) xnrm[r] = zn[ti * 128 + ty * 8 + r];
#pragma unroll
    for (int s = 0; s < 8; ++s) ynrm[s] = zn[tj * 128 + tx * 8 + s];

    float lsum = 0.0f;
#pragma unroll
    for (int r = 0; r < 8; ++r)
#pragma unroll
        for (int s = 0; s < 8; ++s) {
            float d2 = fmaf(-2.0f, acc[r][s], xnrm[r] + ynrm[s]);
            lsum += __expf(-d2 * INV_SIGMA);
        }

    red[tid] = (double)lsum;
    __syncthreads();
#pragma unroll
    for (int ofs = 128; ofs > 0; ofs >>= 1) {
        if (tid < ofs) red[tid] += red[tid + ofs];
        __syncthreads();
    }
    if (tid == 0) partials[bid] = red[0] * (double)factor;
}

extern "C" void kernel_launch(void* const* d_in, const int* in_sizes, int n_in,
                              void* d_out, int out_size, void* d_ws, size_t ws_size,
                              hipStream_t stream) {
    const float* x = (const float*)d_in[0];
    const float* y = (const float*)d_in[1];
    float* out = (float*)d_out;

    const size_t zh_bytes = (size_t)TWO_N * DIM * sizeof(unsigned short); // 32 MiB
    const size_t zn_bytes = (size_t)TWO_N * sizeof(float);
    const size_t pt_bytes = (size_t)NBLK2 * sizeof(double);
    const size_t need = zh_bytes + zn_bytes + pt_bytes;

    if (ws_size >= need) {
        unsigned short* zh = (unsigned short*)d_ws;
        float* zn = (float*)((char*)d_ws + zh_bytes);
        double* partials = (double*)((char*)d_ws + zh_bytes + zn_bytes);
        mmd_convert<<<TWO_N / 4, 256, 0, stream>>>(x, y, zh, zn);
        mmd_main8<<<NBLK2, 512, 0, stream>>>(zh, zn, partials);
        mmd_reduce<<<1, 256, 0, stream>>>(partials, out, NBLK2);
    } else {
        float* zn = (float*)d_ws;
        double* partials = (double*)((char*)d_ws + (size_t)TWO_N * sizeof(float));
        mmd_norms_f32<<<TWO_N / 4, 256, 0, stream>>>(x, y, zn);
        mmd_main_f32<<<128 * 129 / 2, 256, 0, stream>>>(x, y, zn, partials);
        mmd_reduce<<<1, 256, 0, stream>>>(partials, out, 128 * 129 / 2);
    }
}